// Round 3
// baseline (118.466 us; speedup 1.0000x reference)
//
#include <hip/hip_runtime.h>

// Problem dims (fixed by setup_inputs): x [B,N,C], adapter dim D, patch grid HxH
#define B_  64
#define N_  1024
#define H_  32
#define C_  768
#define D_  8

__device__ __forceinline__ float qgelu(float v) {
    // v * sigmoid(1.702 v) = v / (1 + exp(-1.702 v))
    return v / (1.0f + __expf(-1.702f * v));
}

// 10-shuffle butterfly reduce over d=8: halve d at xor1/2/4, broadcast 8/16/32.
// On return acc[0] holds, in lane l, the full sum for
// dl(l) = 4*(l&1) + 2*((l>>1)&1) + ((l>>2)&1)   (lanes l and l^8.. identical).
__device__ __forceinline__ void reduce8(float* acc, int lane) {
    {
        const bool hi = lane & 1;
#pragma unroll
        for (int j = 0; j < 4; ++j) {
            const float a = acc[j], b = acc[j + 4];
            acc[j] = hi ? b : a;
            acc[j + 4] = hi ? a : b;
        }
#pragma unroll
        for (int j = 0; j < 4; ++j)
            acc[j] += __shfl_xor(acc[j + 4], 1, 64);
    }
    {
        const bool hi = lane & 2;
#pragma unroll
        for (int j = 0; j < 2; ++j) {
            const float a = acc[j], b = acc[j + 2];
            acc[j] = hi ? b : a;
            acc[j + 2] = hi ? a : b;
        }
#pragma unroll
        for (int j = 0; j < 2; ++j)
            acc[j] += __shfl_xor(acc[j + 2], 2, 64);
    }
    {
        const bool hi = lane & 4;
        const float a = acc[0], b = acc[1];
        acc[0] = hi ? b : a;
        acc[1] = hi ? a : b;
        acc[0] += __shfl_xor(acc[1], 4, 64);
    }
    acc[0] += __shfl_xor(acc[0], 8, 64);
    acc[0] += __shfl_xor(acc[0], 16, 64);
    acc[0] += __shfl_xor(acc[0], 32, 64);
}

// ---------------- Kernel 1: x_down = quick_gelu(x @ Wd + bd) ----------------
// One wave per ROW PAIR. Weight slice in registers (24 float4/lane, filled
// from an LDS transpose once per wave). Per pair: 6 coalesced b128 loads,
// 192 fmac, two independent 10-shuffle reduces (latency-overlapped), one
// 16-lane store (lanes 0-7: row0, lanes 8-15: row1).
__global__ __launch_bounds__(256, 3) void k_down(
    const float* __restrict__ x, const float* __restrict__ Wd,
    const float* __restrict__ bd, float* __restrict__ t1, int nrows)
{
    __shared__ float sW[D_ * C_];   // transposed: sW[d*C_ + c] = Wd[c*D_ + d]
    for (int i = threadIdx.x; i < D_ * C_; i += 256) {
        int d = i / C_, c = i - d * C_;
        sW[i] = Wd[c * D_ + d];
    }
    __syncthreads();

    const int wid  = threadIdx.x >> 6;
    const int lane = threadIdx.x & 63;

    // Per-lane register weight file (96 VGPRs) — one-time LDS cost.
    float4 w[3][D_];
#pragma unroll
    for (int k = 0; k < 3; ++k)
#pragma unroll
        for (int d = 0; d < D_; ++d)
            w[k][d] = *(const float4*)&sW[d * C_ + (lane + k * 64) * 4];

    const int dl = 4 * (lane & 1) + 2 * ((lane >> 1) & 1) + ((lane >> 2) & 1);
    const float bias = bd[dl];

    const int npairs = nrows >> 1;          // nrows is even
    const int stride = gridDim.x * 4;
    for (int p = blockIdx.x * 4 + wid; p < npairs; p += stride) {
        const int r0 = p * 2;
        const float4* x0 = (const float4*)(x + (size_t)r0 * C_);
        const float4* x1 = x0 + (C_ / 4);

        float4 v0[3], v1[3];
#pragma unroll
        for (int k = 0; k < 3; ++k) {
            v0[k] = x0[lane + k * 64];
            v1[k] = x1[lane + k * 64];
        }

        float a0[D_], a1[D_];
#pragma unroll
        for (int d = 0; d < D_; ++d) { a0[d] = 0.0f; a1[d] = 0.0f; }

#pragma unroll
        for (int k = 0; k < 3; ++k) {
#pragma unroll
            for (int d = 0; d < D_; ++d) {
                a0[d] += v0[k].x * w[k][d].x + v0[k].y * w[k][d].y
                       + v0[k].z * w[k][d].z + v0[k].w * w[k][d].w;
                a1[d] += v1[k].x * w[k][d].x + v1[k].y * w[k][d].y
                       + v1[k].z * w[k][d].z + v1[k].w * w[k][d].w;
            }
        }

        reduce8(a0, lane);      // independent chains — scheduler overlaps them
        reduce8(a1, lane);

        if (lane < 16) {
            const float s = (lane & 8) ? a1[0] : a0[0];
            const int   r = r0 + ((lane >> 3) & 1);
            t1[(size_t)r * D_ + dl] = qgelu(s + bias);
        }
    }
}

// ------------- Kernel 2: t2 = quick_gelu(conv3x3(t1) + bc) ------------------
// 4 blocks per image; each block computes an 8-row strip of the 32x32 grid.
// Strip + zero-padded halo (10 rows) staged in LDS. 1 pixel per thread.
__global__ __launch_bounds__(256, 4) void k_conv(
    const float* __restrict__ t1, const float* __restrict__ Wc,
    const float* __restrict__ bc, float* __restrict__ t2)
{
    __shared__ float sIn[10 * H_ * D_];     // 10 rows x 32 cols x 8 ch = 10 KB
    __shared__ float sWc[9 * D_ * D_];      // 2304 B, layout [kh][kw][ci][co]
    __shared__ float sbc[D_];

    const int img   = blockIdx.x >> 2;
    const int strip = blockIdx.x & 3;
    const int h0    = strip * 8;
    const float* in = t1 + (size_t)img * N_ * D_;

    // load 10 rows (h0-1 .. h0+8) with zero pad outside [0,32)
#pragma unroll
    for (int j = 0; j < 10; ++j) {
        const int i  = threadIdx.x + j * 256;   // i in [0, 2560)
        const int lr = i >> 8;                  // local row (32*8 = 256/row)
        const int rem = i & 255;
        const int g  = h0 - 1 + lr;
        sIn[i] = (g >= 0 && g < H_) ? in[(size_t)g * H_ * D_ + rem] : 0.0f;
    }
    for (int i = threadIdx.x; i < 9 * D_ * D_; i += 256) sWc[i] = Wc[i];
    if (threadIdx.x < D_) sbc[threadIdx.x] = bc[threadIdx.x];
    __syncthreads();

    const int lh = threadIdx.x >> 5;            // 0..7 strip row
    const int w  = threadIdx.x & 31;            // 0..31 col
    float acc[D_];
#pragma unroll
    for (int co = 0; co < D_; ++co) acc[co] = sbc[co];

#pragma unroll
    for (int kh = 0; kh < 3; ++kh) {
        const int lrow = lh + kh;               // rows are zero-padded in LDS
#pragma unroll
        for (int kw = 0; kw < 3; ++kw) {
            const int ww = w + kw - 1;
            if (ww < 0 || ww >= H_) continue;
            const float* ip = &sIn[(lrow * H_ + ww) * D_];
            const float* wp = &sWc[(kh * 3 + kw) * D_ * D_];
#pragma unroll
            for (int ci = 0; ci < D_; ++ci) {
                const float iv = ip[ci];
#pragma unroll
                for (int co = 0; co < D_; ++co)
                    acc[co] += iv * wp[ci * D_ + co];
            }
        }
    }
    float4 o0, o1;
    o0.x = qgelu(acc[0]); o0.y = qgelu(acc[1]);
    o0.z = qgelu(acc[2]); o0.w = qgelu(acc[3]);
    o1.x = qgelu(acc[4]); o1.y = qgelu(acc[5]);
    o1.z = qgelu(acc[6]); o1.w = qgelu(acc[7]);
    float* tp = t2 + ((size_t)img * N_ + (size_t)(h0 + lh) * H_ + w) * D_;
    *(float4*)tp       = o0;
    *(float4*)(tp + 4) = o1;
}

// ---------------- Kernel 3: out = t2 @ Wu + bu ------------------------------
// One wave per row. Each lane OWNS 3 output float4 columns (c4 = lane+j*64);
// its Wu slice (96 VGPR) + bias (12 VGPR) live in registers, loaded once
// from global (L2-hot). The 8 t2 row values arrive as two wave-uniform
// broadcast float4 loads. Zero LDS -> purely write-bound.
__global__ __launch_bounds__(256, 3) void k_up(
    const float* __restrict__ t2, const float* __restrict__ Wu,
    const float* __restrict__ bu, float* __restrict__ out, int nrows)
{
    const int wid  = threadIdx.x >> 6;
    const int lane = threadIdx.x & 63;

    float4 w[3][D_];
    float4 bias[3];
#pragma unroll
    for (int j = 0; j < 3; ++j) {
        bias[j] = *(const float4*)&bu[(lane + j * 64) * 4];
#pragma unroll
        for (int d = 0; d < D_; ++d)
            w[j][d] = *(const float4*)&Wu[d * C_ + (lane + j * 64) * 4];
    }

    const int stride = gridDim.x * 4;
    for (int row = blockIdx.x * 4 + wid; row < nrows; row += stride) {
        const float4* rp = (const float4*)(t2 + (size_t)row * D_);
        const float4 ra = rp[0];
        const float4 rb = rp[1];
        const float rv[D_] = { ra.x, ra.y, ra.z, ra.w, rb.x, rb.y, rb.z, rb.w };

#pragma unroll
        for (int j = 0; j < 3; ++j) {
            float4 o = bias[j];
#pragma unroll
            for (int d = 0; d < D_; ++d) {
                o.x += rv[d] * w[j][d].x;
                o.y += rv[d] * w[j][d].y;
                o.z += rv[d] * w[j][d].z;
                o.w += rv[d] * w[j][d].w;
            }
            *(float4*)&out[(size_t)row * C_ + (size_t)(lane + j * 64) * 4] = o;
        }
    }
}

extern "C" void kernel_launch(void* const* d_in, const int* in_sizes, int n_in,
                              void* d_out, int out_size, void* d_ws, size_t ws_size,
                              hipStream_t stream) {
    const float* x  = (const float*)d_in[0];
    const float* Wd = (const float*)d_in[1];
    const float* bd = (const float*)d_in[2];
    const float* Wc = (const float*)d_in[3];
    const float* bc = (const float*)d_in[4];
    const float* Wu = (const float*)d_in[5];
    const float* bu = (const float*)d_in[6];
    float* out = (float*)d_out;

    const int nrows = B_ * N_;                  // 65536
    float* t1 = (float*)d_ws;                   // [nrows][D_]  (2 MB)
    float* t2 = t1 + (size_t)nrows * D_;        // [nrows][D_]  (2 MB)

    // K1: 3 blocks/CU resident (VGPR ~155), grid-stride over 32768 row pairs.
    k_down<<<768, 256, 0, stream>>>(x, Wd, bd, t1, nrows);
    // K2: 4 blocks per image
    k_conv<<<B_ * 4, 256, 0, stream>>>(t1, Wc, bc, t2);
    // K3: register-weight, LDS-free; 3 blocks/CU, grid-stride over rows.
    k_up<<<768, 256, 0, stream>>>(t2, Wu, bu, out, nrows);
}